// Round 3
// baseline (272.029 us; speedup 1.0000x reference)
//
#include <hip/hip_runtime.h>
#include <cstddef>

// MultiHeadAttentionLayer: B=2, S=2048, D=1024, H=16, DEPTH=64
// R2: (1) base-2 softmax (Q pre-scaled by 0.125/ln2 in projection epilogue,
//     mask by -1e9/ln2) + defer-max rescale (T13) + native bf16 casts -> big
//     VALU cut in attn (was VALUBusy 50%).
//     (2) 2-phase double-buffered staging (T3 minimum) in attn AND gemm:
//     prefetch tile t+1 via global_load_lds before computing t, one barrier
//     per tile. T14 split for the f32 A-path and mask.
//     (3) setprio around attn MFMA clusters (T5). (4) XCD-bijective swizzle
//     in attn: each XCD owns 4 heads -> K/V L2-resident.

namespace {

constexpr int Ss = 2048;
constexpr int Dd = 1024;
constexpr int Mm = 4096;  // B*S
constexpr int NT = Ss / 64;

typedef unsigned short u16;
typedef __attribute__((ext_vector_type(8))) __bf16 bf16x8;
typedef __attribute__((ext_vector_type(4))) float f32x4;

__device__ __forceinline__ u16 bfc(float f) {
  __bf16 h = (__bf16)f;  // RNE; compiler pairs into v_cvt_pk_bf16_f32
  return __builtin_bit_cast(u16, h);
}

__device__ __forceinline__ void gload_lds16(const void* g, void* l) {
  __builtin_amdgcn_global_load_lds(
      (__attribute__((address_space(1))) void*)g,
      (__attribute__((address_space(3))) void*)l, 16, 0, 0);
}

__device__ __forceinline__ f32x4 mfma16(bf16x8 a, bf16x8 b, f32x4 c) {
  return __builtin_amdgcn_mfma_f32_16x16x32_bf16(a, b, c, 0, 0, 0);
}

__device__ __forceinline__ float exp2_fast(float x) {
  return __builtin_amdgcn_exp2f(x);
}

// swizzled u16 index within a [rows][64 u16] LDS tile (128B rows, 16B chunks)
__device__ __forceinline__ int swz(int row, int col) {
  return row * 64 + ((((col >> 3) ^ (row & 7)) << 3) | (col & 7));
}
// pre-swizzled source column chunk for global_load_lds staging of 8 rows
__device__ __forceinline__ int src_col(int lane) {
  return ((lane & 7) ^ (lane >> 3)) * 8;
}

// ---------------------------------------------------------------- transpose
__global__ __launch_bounds__(256) void wt_transpose(const float* __restrict__ W0,
                                                    const float* __restrict__ W1,
                                                    const float* __restrict__ W2,
                                                    u16* __restrict__ wsbase) {
  const float* W = (blockIdx.z == 0) ? W0 : (blockIdx.z == 1) ? W1 : W2;
  u16* WT = wsbase + (size_t)blockIdx.z * (1024 * 1024);
  __shared__ float tile[32][33];
  const int tx = threadIdx.x & 31;
  const int ty = threadIdx.x >> 5;  // 0..7
  const int n0 = blockIdx.x * 32;
  const int k0 = blockIdx.y * 32;
#pragma unroll
  for (int i = 0; i < 4; ++i)
    tile[ty + i * 8][tx] = W[(size_t)(k0 + ty + i * 8) * 1024 + n0 + tx];
  __syncthreads();
#pragma unroll
  for (int i = 0; i < 4; ++i)
    WT[(size_t)(n0 + ty + i * 8) * 1024 + k0 + tx] = bfc(tile[tx][ty + i * 8]);
}

// ---------------------------------------------------------------- GEMM (B^T)
// C[M,N] = (A[M,K] @ BT[N,K]^T + bias[N]) * cscale.  128x128 tile, BK=64,
// 4 waves, double-buffered LDS, one barrier per K-step.
template <bool A_F32, bool C_F32, bool C_TRANS = false>
__global__ __launch_bounds__(256) void gemm_bt(const void* __restrict__ Ap,
                                               const u16* __restrict__ Bt,
                                               const float* __restrict__ bias,
                                               void* __restrict__ Cp,
                                               int M, int N, int K, float cscale) {
  __shared__ u16 As[2][128 * 64];
  __shared__ u16 Bs[2][128 * 64];
  const int tid = threadIdx.x;
  const int wid = tid >> 6;
  const int lane = tid & 63;
  const int g = lane >> 4;
  const int lr = lane & 15;
  const int n0 = blockIdx.x * 128;
  const int m0 = blockIdx.y * 128;
  const int wr = wid >> 1, wc = wid & 1;
  const int KT = K >> 6;

  const f32x4 zero = {0.f, 0.f, 0.f, 0.f};
  f32x4 acc[4][4];
#pragma unroll
  for (int m = 0; m < 4; ++m)
#pragma unroll
    for (int n = 0; n < 4; ++n) acc[m][n] = zero;

  float4 areg[8];

  auto loadA_f32 = [&](int kt) {
    const float* A = (const float*)Ap;
#pragma unroll
    for (int i = 0; i < 8; ++i) {
      int e = i * 256 + tid;
      int row = e >> 4;
      int c4 = (e & 15) << 2;
      areg[i] = *(const float4*)(&A[(size_t)(m0 + row) * K + kt * 64 + c4]);
    }
  };
  auto writeA_f32 = [&](int buf) {
#pragma unroll
    for (int i = 0; i < 8; ++i) {
      int e = i * 256 + tid;
      int row = e >> 4;
      int c4 = (e & 15) << 2;
      ushort4 o4 = make_ushort4(bfc(areg[i].x), bfc(areg[i].y),
                                bfc(areg[i].z), bfc(areg[i].w));
      *(ushort4*)(&As[buf][swz(row, c4)]) = o4;
    }
  };
  auto stageA_lds = [&](int kt, int buf) {
    const u16* A = (const u16*)Ap;
#pragma unroll
    for (int j = 0; j < 4; ++j) {
      int rb = (wid * 4 + j) * 8;
      gload_lds16(&A[(size_t)(m0 + rb + (lane >> 3)) * K + kt * 64 + src_col(lane)],
                  &As[buf][rb * 64]);
    }
  };
  auto stageB = [&](int kt, int buf) {
#pragma unroll
    for (int j = 0; j < 4; ++j) {
      int rb = (wid * 4 + j) * 8;
      gload_lds16(&Bt[(size_t)(n0 + rb + (lane >> 3)) * K + kt * 64 + src_col(lane)],
                  &Bs[buf][rb * 64]);
    }
  };

  // prologue: stage tile 0
  if constexpr (A_F32) loadA_f32(0); else stageA_lds(0, 0);
  stageB(0, 0);
  if constexpr (A_F32) writeA_f32(0);
  __syncthreads();

  int cur = 0;
  for (int kt = 0; kt < KT; ++kt) {
    const bool more = (kt + 1) < KT;
    if (more) {
      if constexpr (A_F32) loadA_f32(kt + 1); else stageA_lds(kt + 1, cur ^ 1);
      stageB(kt + 1, cur ^ 1);
    }
    const u16* as = As[cur];
    const u16* bs = Bs[cur];
#pragma unroll
    for (int kk = 0; kk < 2; ++kk) {
      bf16x8 a[4], b[4];
#pragma unroll
      for (int m = 0; m < 4; ++m)
        a[m] = *(const bf16x8*)(&as[swz(wr * 64 + m * 16 + lr, kk * 32 + g * 8)]);
#pragma unroll
      for (int n = 0; n < 4; ++n)
        b[n] = *(const bf16x8*)(&bs[swz(wc * 64 + n * 16 + lr, kk * 32 + g * 8)]);
#pragma unroll
      for (int m = 0; m < 4; ++m)
#pragma unroll
        for (int n = 0; n < 4; ++n) acc[m][n] = mfma16(a[m], b[n], acc[m][n]);
    }
    if (more) {
      if constexpr (A_F32) writeA_f32(cur ^ 1);  // T14: write late, after compute
    }
    __syncthreads();
    cur ^= 1;
  }

  // epilogue: C/D layout col=lane&15, row=(lane>>4)*4+reg
#pragma unroll
  for (int n = 0; n < 4; ++n) {
    const int col = n0 + wc * 64 + n * 16 + lr;
    const float bv = bias[col];
#pragma unroll
    for (int m = 0; m < 4; ++m) {
      const int rowb = m0 + wr * 64 + m * 16 + g * 4;
      if constexpr (C_TRANS) {
        ushort4 o4 = make_ushort4(bfc((acc[m][n][0] + bv) * cscale),
                                  bfc((acc[m][n][1] + bv) * cscale),
                                  bfc((acc[m][n][2] + bv) * cscale),
                                  bfc((acc[m][n][3] + bv) * cscale));
        *(ushort4*)(&((u16*)Cp)[(size_t)col * M + rowb]) = o4;
      } else {
#pragma unroll
        for (int r = 0; r < 4; ++r) {
          float val = (acc[m][n][r] + bv) * cscale;
          if constexpr (C_F32)
            ((float*)Cp)[(size_t)(rowb + r) * N + col] = val;
          else
            ((u16*)Cp)[(size_t)(rowb + r) * N + col] = bfc(val);
        }
      }
    }
  }
}

// ---------------------------------------------------------------- attention
// Q pre-scaled by 0.125/ln2 -> all softmax math in base-2 (exp2).
// Double-buffered K/V staging, one barrier per tile, defer-max rescale.
__global__ __launch_bounds__(256) void attn(const u16* __restrict__ Qp,
                                            const u16* __restrict__ Kp,
                                            const u16* __restrict__ VpT,
                                            const float* __restrict__ mask,
                                            u16* __restrict__ Op) {
  __shared__ u16 Ks[2][64 * 64];   // [key][d]  (swizzled)
  __shared__ u16 Vt[2][64 * 64];   // [d][key]  (swizzled)
  __shared__ u16 Ps[4][16 * 64];   // per-wave P tile (swizzled)
  __shared__ float ms[2][64];      // mask * (-1e9/ln2)
  const int tid = threadIdx.x;
  const int wid = tid >> 6;
  const int lane = tid & 63;
  const int g = lane >> 4;
  const int lr = lane & 15;
  // XCD-bijective swizzle: each XCD owns 4 consecutive bh (K/V fit its L2)
  const int lin = (int)(blockIdx.x + (blockIdx.y << 5));  // grid (32,32)
  const int wl = (lin & 7) * 128 + (lin >> 3);
  const int q0 = (wl & 31) * 64;
  const int bh = wl >> 5;
  const int b = bh >> 4;
  const int h = bh & 15;
  const size_t base = ((size_t)b * Ss) * Dd + (size_t)h * 64;
  const size_t vbase = (size_t)h * 64 * Mm + (size_t)b * Ss;
  constexpr float NEG2 = -1.442695041e9f;  // -1e9/ln2

  bf16x8 qf[2];
  {
    const int row = q0 + wid * 16 + lr;
#pragma unroll
    for (int kk = 0; kk < 2; ++kk)
      qf[kk] = *(const bf16x8*)(&Qp[base + (size_t)row * Dd + kk * 32 + g * 8]);
  }

  const f32x4 zero = {0.f, 0.f, 0.f, 0.f};
  f32x4 o[4];
#pragma unroll
  for (int i = 0; i < 4; ++i) o[i] = zero;
  float mrun[4], lrun[4];
#pragma unroll
  for (int r = 0; r < 4; ++r) {
    mrun[r] = -1e30f;
    lrun[r] = 0.f;
  }

  auto stageKV = [&](int t, int buf) {
    const int key0 = t * 64;
#pragma unroll
    for (int j = 0; j < 2; ++j) {
      int rb = (wid * 2 + j) * 8;
      gload_lds16(&Kp[base + (size_t)(key0 + rb + (lane >> 3)) * Dd + src_col(lane)],
                  &Ks[buf][rb * 64]);
      gload_lds16(&VpT[vbase + (size_t)(rb + (lane >> 3)) * Mm + key0 + src_col(lane)],
                  &Vt[buf][rb * 64]);
    }
  };

  // prologue
  stageKV(0, 0);
  float msr = 0.f;
  if (tid < 64) {
    msr = mask[(size_t)b * Ss + tid];
    ms[0][tid] = msr * NEG2;
  }
  __syncthreads();

  int cur = 0;
  for (int t = 0; t < NT; ++t) {
    const bool more = (t + 1) < NT;
    if (more) {
      stageKV(t + 1, cur ^ 1);                       // loads fly under compute
      if (tid < 64) msr = mask[(size_t)b * Ss + (t + 1) * 64 + tid];
    }
    // S = Q K^T (base-2 logits since Q pre-scaled)
    f32x4 sa[4];
#pragma unroll
    for (int i = 0; i < 4; ++i) sa[i] = zero;
    __builtin_amdgcn_s_setprio(1);
#pragma unroll
    for (int kk = 0; kk < 2; ++kk)
#pragma unroll
      for (int sub = 0; sub < 4; ++sub) {
        bf16x8 kf = *(const bf16x8*)(&Ks[cur][swz(sub * 16 + lr, kk * 32 + g * 8)]);
        sa[sub] = mfma16(qf[kk], kf, sa[sub]);
      }
    __builtin_amdgcn_s_setprio(0);

    float lg[4][4];
#pragma unroll
    for (int sub = 0; sub < 4; ++sub) {
      const float mk = ms[cur][sub * 16 + lr];
#pragma unroll
      for (int r = 0; r < 4; ++r) lg[sub][r] = sa[sub][r] + mk;
    }
    // row maxima + defer-max check
    float rm[4];
    bool need = false;
#pragma unroll
    for (int r = 0; r < 4; ++r) {
      rm[r] = fmaxf(fmaxf(lg[0][r], lg[1][r]), fmaxf(lg[2][r], lg[3][r]));
#pragma unroll
      for (int ofs = 1; ofs < 16; ofs <<= 1) rm[r] = fmaxf(rm[r], __shfl_xor(rm[r], ofs));
      need = need || (rm[r] > mrun[r] + 10.0f);
    }
    if (__any(need)) {
#pragma unroll
      for (int r = 0; r < 4; ++r) {
        const float mnew = fmaxf(mrun[r], rm[r]);
        const float corr = exp2_fast(mrun[r] - mnew);
        lrun[r] *= corr;
#pragma unroll
        for (int dsub = 0; dsub < 4; ++dsub) o[dsub][r] *= corr;
        mrun[r] = mnew;
      }
    }
#pragma unroll
    for (int r = 0; r < 4; ++r) {
      float ps = 0.f;
#pragma unroll
      for (int sub = 0; sub < 4; ++sub) {
        float p = exp2_fast(lg[sub][r] - mrun[r]);
        lg[sub][r] = p;
        ps += p;
      }
#pragma unroll
      for (int ofs = 1; ofs < 16; ofs <<= 1) ps += __shfl_xor(ps, ofs);
      lrun[r] += ps;
    }
    // P -> LDS (per-wave, no barrier needed)
#pragma unroll
    for (int sub = 0; sub < 4; ++sub)
#pragma unroll
      for (int r = 0; r < 4; ++r)
        Ps[wid][swz(g * 4 + r, sub * 16 + lr)] = bfc(lg[sub][r]);
    // O += P V
    __builtin_amdgcn_s_setprio(1);
#pragma unroll
    for (int kc = 0; kc < 2; ++kc) {
      bf16x8 pf = *(const bf16x8*)(&Ps[wid][swz(lr, kc * 32 + g * 8)]);
#pragma unroll
      for (int dsub = 0; dsub < 4; ++dsub) {
        bf16x8 vf = *(const bf16x8*)(&Vt[cur][swz(dsub * 16 + lr, kc * 32 + g * 8)]);
        o[dsub] = mfma16(pf, vf, o[dsub]);
      }
    }
    __builtin_amdgcn_s_setprio(0);
    if (more && tid < 64) ms[cur ^ 1][tid] = msr * NEG2;  // T14: write late
    __syncthreads();
    cur ^= 1;
  }
  // normalize + store bf16
#pragma unroll
  for (int dsub = 0; dsub < 4; ++dsub) {
    const int col = h * 64 + dsub * 16 + lr;
#pragma unroll
    for (int r = 0; r < 4; ++r) {
      const int row = q0 + wid * 16 + g * 4 + r;
      Op[((size_t)b * Ss + row) * Dd + col] = bfc(o[dsub][r] / lrun[r]);
    }
  }
}

}  // namespace

extern "C" void kernel_launch(void* const* d_in, const int* in_sizes, int n_in,
                              void* d_out, int out_size, void* d_ws, size_t ws_size,
                              hipStream_t stream) {
  (void)in_sizes; (void)n_in; (void)out_size; (void)ws_size;
  const float* v = (const float*)d_in[0];
  const float* q = (const float*)d_in[1];
  const float* k = (const float*)d_in[2];
  const float* mask = (const float*)d_in[3];
  const float* Wq = (const float*)d_in[4];
  const float* bq = (const float*)d_in[5];
  const float* Wv = (const float*)d_in[6];
  const float* bv = (const float*)d_in[7];
  const float* Wo = (const float*)d_in[8];
  const float* bo = (const float*)d_in[9];
  float* out = (float*)d_out;

  u16* ws = (u16*)d_ws;
  u16* WqT = ws;
  u16* WvT = WqT + 1024 * 1024;
  u16* WoT = WvT + 1024 * 1024;
  u16* Qp = WoT + 1024 * 1024;
  u16* Kp = Qp + 4096 * 1024;
  u16* VpT = Kp + 4096 * 1024;   // V^T: [1024][4096]
  u16* AO = VpT + 4096 * 1024;   // total 38 MB

  constexpr float QSCALE = 0.18033688f;  // 0.125 / ln2 (base-2 softmax)

  wt_transpose<<<dim3(32, 32, 3), 256, 0, stream>>>(Wq, Wv, Wo, ws);
  // NOTE: reference projects K with the QUERY weights (wQuery(k)).
  gemm_bt<true, false><<<dim3(8, 32), 256, 0, stream>>>(q, WqT, bq, Qp, 4096, 1024, 1024, QSCALE);
  gemm_bt<true, false><<<dim3(8, 32), 256, 0, stream>>>(k, WqT, bq, Kp, 4096, 1024, 1024, 1.0f);
  gemm_bt<true, false, true><<<dim3(8, 32), 256, 0, stream>>>(v, WvT, bv, VpT, 4096, 1024, 1024, 1.0f);
  attn<<<dim3(Ss / 64, 2 * 16), 256, 0, stream>>>(Qp, Kp, VpT, mask, AO);
  gemm_bt<false, true><<<dim3(8, 32), 256, 0, stream>>>(AO, WoT, bo, out, 4096, 1024, 1024, 1.0f);
}

// Round 4
// 160.888 us; speedup vs baseline: 1.6908x; 1.6908x over previous
//
#include <hip/hip_runtime.h>
#include <cstddef>

// MultiHeadAttentionLayer: B=2, S=2048, D=1024, H=16, DEPTH=64
// R3: (1) attn rewritten to 32x32x16-MFMA swapped-QK^T structure (m214-style):
//     lane holds a full 64-key P-row for one q-row -> in-register softmax
//     (reg max/sum tree + one shfl_xor(32)), P packed to bf16 via paired casts
//     + permlane32_swap feeding PV's A-operand directly. No P LDS roundtrip.
//     (2) Q/K/V projections fused into ONE dispatch (768 blocks = 3/CU) with
//     single-buffered LDS. (3) O-GEMM on 128x64 tiles (512 blocks = 2/CU).

namespace {

constexpr int Ss = 2048;
constexpr int Dd = 1024;
constexpr int Mm = 4096;  // B*S
constexpr int NT = Ss / 64;
constexpr float QSCALE = 0.18033688f;   // 0.125 / ln2  (base-2 softmax)
constexpr float NEG2 = -1.442695041e9f; // -1e9 / ln2

typedef unsigned short u16;
typedef __attribute__((ext_vector_type(8))) __bf16 bf16x8;
typedef __attribute__((ext_vector_type(4))) float f32x4;
typedef __attribute__((ext_vector_type(16))) float f32x16;
typedef __attribute__((ext_vector_type(4))) unsigned int u32x4;
typedef __attribute__((ext_vector_type(2))) unsigned int u32x2;

__device__ __forceinline__ u16 bfc(float f) {
  __bf16 h = (__bf16)f;  // RNE; pairs into v_cvt_pk_bf16_f32
  return __builtin_bit_cast(u16, h);
}
__device__ __forceinline__ unsigned pack2(float lo, float hi) {
  return (unsigned)bfc(lo) | ((unsigned)bfc(hi) << 16);
}

__device__ __forceinline__ void gload_lds16(const void* g, void* l) {
  __builtin_amdgcn_global_load_lds(
      (__attribute__((address_space(1))) void*)g,
      (__attribute__((address_space(3))) void*)l, 16, 0, 0);
}

__device__ __forceinline__ f32x4 mfma16(bf16x8 a, bf16x8 b, f32x4 c) {
  return __builtin_amdgcn_mfma_f32_16x16x32_bf16(a, b, c, 0, 0, 0);
}
__device__ __forceinline__ f32x16 mfma32(bf16x8 a, bf16x8 b, f32x16 c) {
  return __builtin_amdgcn_mfma_f32_32x32x16_bf16(a, b, c, 0, 0, 0);
}
__device__ __forceinline__ float exp2_fast(float x) {
  return __builtin_amdgcn_exp2f(x);
}

// permlane32_swap: new_a[l<32]=a[l], new_a[l>=32]=b[l-32];
//                  new_b[l<32]=a[l+32], new_b[l>=32]=b[l]
__device__ __forceinline__ void pl32swap(unsigned& a, unsigned& b) {
#if __has_builtin(__builtin_amdgcn_permlane32_swap)
  u32x2 r = __builtin_amdgcn_permlane32_swap(a, b, false, false);
  a = r[0];
  b = r[1];
#else
  unsigned ax = (unsigned)__shfl_xor((int)a, 32);
  unsigned bx = (unsigned)__shfl_xor((int)b, 32);
  bool hi = (threadIdx.x & 63) >= 32;
  unsigned na = hi ? bx : a;
  unsigned nb = hi ? b : ax;
  a = na;
  b = nb;
#endif
}

// swizzled u16 index within a [rows][64 u16] LDS tile (128B rows, 16B chunks)
__device__ __forceinline__ int swz(int row, int col) {
  return row * 64 + ((((col >> 3) ^ (row & 7)) << 3) | (col & 7));
}
// pre-swizzled source column for global_load_lds staging of 8 rows
__device__ __forceinline__ int src_col(int lane) {
  return ((lane & 7) ^ (lane >> 3)) * 8;
}

// ---------------------------------------------------------------- transpose
__global__ __launch_bounds__(256) void wt_transpose(const float* __restrict__ W0,
                                                    const float* __restrict__ W1,
                                                    const float* __restrict__ W2,
                                                    u16* __restrict__ wsbase) {
  const float* W = (blockIdx.z == 0) ? W0 : (blockIdx.z == 1) ? W1 : W2;
  u16* WT = wsbase + (size_t)blockIdx.z * (1024 * 1024);
  __shared__ float tile[32][33];
  const int tx = threadIdx.x & 31;
  const int ty = threadIdx.x >> 5;
  const int n0 = blockIdx.x * 32;
  const int k0 = blockIdx.y * 32;
#pragma unroll
  for (int i = 0; i < 4; ++i)
    tile[ty + i * 8][tx] = W[(size_t)(k0 + ty + i * 8) * 1024 + n0 + tx];
  __syncthreads();
#pragma unroll
  for (int i = 0; i < 4; ++i)
    WT[(size_t)(n0 + ty + i * 8) * 1024 + k0 + tx] = bfc(tile[tx][ty + i * 8]);
}

// ---------------------------------------------------------------- fused QKV projection
// z=0: Qp = bf16((q@Wq + bq) * QSCALE); z=1: Kp = bf16(k@Wq + bq)  [ref quirk];
// z=2: VpT = bf16(v@Wv + bv) stored TRANSPOSED ([1024][4096]).
// 128x128 tile, BK=64, 4 waves, single-buffered LDS. 768 blocks = 3/CU.
__global__ __launch_bounds__(256) void proj_qkv(
    const float* __restrict__ q, const float* __restrict__ k,
    const float* __restrict__ v, const u16* __restrict__ WqT,
    const u16* __restrict__ WvT, const float* __restrict__ bq,
    const float* __restrict__ bv, u16* __restrict__ Qp, u16* __restrict__ Kp,
    u16* __restrict__ VpT) {
  constexpr int K = 1024, N = 1024, M = 4096;
  __shared__ u16 As[128 * 64];
  __shared__ u16 Bs[128 * 64];
  const int z = blockIdx.z;
  const float* A = (z == 0) ? q : (z == 1) ? k : v;
  const u16* Bt = (z == 2) ? WvT : WqT;
  const float* bias = (z == 2) ? bv : bq;
  const float cscale = (z == 0) ? QSCALE : 1.0f;

  const int tid = threadIdx.x;
  const int wid = tid >> 6;
  const int lane = tid & 63;
  const int g = lane >> 4;
  const int lr = lane & 15;
  const int n0 = blockIdx.x * 128;
  const int m0 = blockIdx.y * 128;
  const int wr = wid >> 1, wc = wid & 1;

  const f32x4 zero = {0.f, 0.f, 0.f, 0.f};
  f32x4 acc[4][4];
#pragma unroll
  for (int m = 0; m < 4; ++m)
#pragma unroll
    for (int n = 0; n < 4; ++n) acc[m][n] = zero;

  for (int k0 = 0; k0 < K; k0 += 64) {
    float4 areg[8];
#pragma unroll
    for (int i = 0; i < 8; ++i) {
      int e = i * 256 + tid;
      int row = e >> 4;
      int c4 = (e & 15) << 2;
      areg[i] = *(const float4*)(&A[(size_t)(m0 + row) * K + k0 + c4]);
    }
#pragma unroll
    for (int j = 0; j < 4; ++j) {
      int rb = (wid * 4 + j) * 8;
      gload_lds16(&Bt[(size_t)(n0 + rb + (lane >> 3)) * K + k0 + src_col(lane)],
                  &Bs[rb * 64]);
    }
#pragma unroll
    for (int i = 0; i < 8; ++i) {
      int e = i * 256 + tid;
      int row = e >> 4;
      int c4 = (e & 15) << 2;
      ushort4 o4 = make_ushort4(bfc(areg[i].x), bfc(areg[i].y), bfc(areg[i].z),
                                bfc(areg[i].w));
      *(ushort4*)(&As[swz(row, c4)]) = o4;
    }
    __syncthreads();
#pragma unroll
    for (int kk = 0; kk < 2; ++kk) {
      bf16x8 a[4], b[4];
#pragma unroll
      for (int m = 0; m < 4; ++m)
        a[m] = *(const bf16x8*)(&As[swz(wr * 64 + m * 16 + lr, kk * 32 + g * 8)]);
#pragma unroll
      for (int n = 0; n < 4; ++n)
        b[n] = *(const bf16x8*)(&Bs[swz(wc * 64 + n * 16 + lr, kk * 32 + g * 8)]);
#pragma unroll
      for (int m = 0; m < 4; ++m)
#pragma unroll
        for (int n = 0; n < 4; ++n) acc[m][n] = mfma16(a[m], b[n], acc[m][n]);
    }
    __syncthreads();
  }

#pragma unroll
  for (int n = 0; n < 4; ++n) {
    const int col = n0 + wc * 64 + n * 16 + lr;
    const float bv_ = bias[col];
#pragma unroll
    for (int m = 0; m < 4; ++m) {
      const int rowb = m0 + wr * 64 + m * 16 + g * 4;
      if (z == 2) {
        ushort4 o4 = make_ushort4(bfc(acc[m][n][0] + bv_), bfc(acc[m][n][1] + bv_),
                                  bfc(acc[m][n][2] + bv_), bfc(acc[m][n][3] + bv_));
        *(ushort4*)(&VpT[(size_t)col * M + rowb]) = o4;
      } else {
        u16* Cp = (z == 0) ? Qp : Kp;
#pragma unroll
        for (int r = 0; r < 4; ++r)
          Cp[(size_t)(rowb + r) * N + col] = bfc((acc[m][n][r] + bv_) * cscale);
      }
    }
  }
}

// ---------------------------------------------------------------- O-GEMM
// out = AO @ WoT^T + bo (f32). 128x64 tile, 4 waves (each 32x64), 512 blocks.
__global__ __launch_bounds__(256) void gemm_o(const u16* __restrict__ Ap,
                                              const u16* __restrict__ Bt,
                                              const float* __restrict__ bias,
                                              float* __restrict__ Cp) {
  constexpr int K = 1024, N = 1024;
  __shared__ u16 As[128 * 64];
  __shared__ u16 Bs[64 * 64];
  const int tid = threadIdx.x;
  const int wid = tid >> 6;
  const int lane = tid & 63;
  const int g = lane >> 4;
  const int lr = lane & 15;
  const int n0 = blockIdx.x * 64;
  const int m0 = blockIdx.y * 128;

  const f32x4 zero = {0.f, 0.f, 0.f, 0.f};
  f32x4 acc[2][4];
#pragma unroll
  for (int m = 0; m < 2; ++m)
#pragma unroll
    for (int n = 0; n < 4; ++n) acc[m][n] = zero;

  for (int k0 = 0; k0 < K; k0 += 64) {
#pragma unroll
    for (int j = 0; j < 4; ++j) {
      int rb = (wid * 4 + j) * 8;
      gload_lds16(&Ap[(size_t)(m0 + rb + (lane >> 3)) * K + k0 + src_col(lane)],
                  &As[rb * 64]);
    }
#pragma unroll
    for (int j = 0; j < 2; ++j) {
      int rb = (wid * 2 + j) * 8;
      gload_lds16(&Bt[(size_t)(n0 + rb + (lane >> 3)) * K + k0 + src_col(lane)],
                  &Bs[rb * 64]);
    }
    __syncthreads();
#pragma unroll
    for (int kk = 0; kk < 2; ++kk) {
      bf16x8 a[2], b[4];
#pragma unroll
      for (int m = 0; m < 2; ++m)
        a[m] = *(const bf16x8*)(&As[swz(wid * 32 + m * 16 + lr, kk * 32 + g * 8)]);
#pragma unroll
      for (int n = 0; n < 4; ++n)
        b[n] = *(const bf16x8*)(&Bs[swz(n * 16 + lr, kk * 32 + g * 8)]);
#pragma unroll
      for (int m = 0; m < 2; ++m)
#pragma unroll
        for (int n = 0; n < 4; ++n) acc[m][n] = mfma16(a[m], b[n], acc[m][n]);
    }
    __syncthreads();
  }
#pragma unroll
  for (int n = 0; n < 4; ++n) {
    const int col = n0 + n * 16 + lr;
    const float bv_ = bias[col];
#pragma unroll
    for (int m = 0; m < 2; ++m) {
      const int rowb = m0 + wid * 32 + m * 16 + g * 4;
#pragma unroll
      for (int r = 0; r < 4; ++r)
        Cp[(size_t)(rowb + r) * N + col] = acc[m][n][r] + bv_;
    }
  }
}

// ---------------------------------------------------------------- attention
// 32x32x16 swapped-QK^T flash attention. Block = 4 waves x 32 q-rows = 128
// rows; grid (16, 32) = 512 blocks. Per lane: q-row = lane&31; S^T C-layout
// gives the full 64-key P-row in 32 f32 regs (keys crow(r,hi)+32*sub,
// crow = (r&3)+8*(r>>2)+4*hi). Softmax fully in-register; P packed to bf16
// A-fragments via paired casts + permlane32_swap (T12). O accumulates in
// 2x f32x16 (rows crow(r,hi), col = dsub*32+lane&31).
__global__ __launch_bounds__(256) void attn32(const u16* __restrict__ Qp,
                                              const u16* __restrict__ Kp,
                                              const u16* __restrict__ VpT,
                                              const float* __restrict__ mask,
                                              u16* __restrict__ Op) {
  __shared__ u16 Ks[2][64 * 64];  // [key][d]  (swizzled)
  __shared__ u16 Vt[2][64 * 64];  // [d][key]  (swizzled)
  __shared__ float ms[2][64];     // mask * (-1e9/ln2)
  __shared__ float redbuf[4][32]; // per-wave row-broadcast buffer
  const int tid = threadIdx.x;
  const int wid = tid >> 6;
  const int lane = tid & 63;
  const int l31 = lane & 31;
  const int hi = lane >> 5;
  // XCD-bijective swizzle: each XCD owns 4 heads (K/V L2-resident)
  const int lin = (int)(blockIdx.x + (blockIdx.y << 4));  // grid (16,32)
  const int wl = (lin & 7) * 64 + (lin >> 3);
  const int qt = wl & 15;
  const int bh = wl >> 4;
  const int b = bh >> 4;
  const int h = bh & 15;
  const int q0 = qt * 128;
  const size_t base = ((size_t)b * Ss) * Dd + (size_t)h * 64;
  const size_t vbase = (size_t)h * 64 * Mm + (size_t)b * Ss;
  const int qrow = q0 + wid * 32 + l31;

  // Q fragments (B-operand): col=qrow, k(d) = ks*16 + hi*8 .. +8
  bf16x8 qf[4];
#pragma unroll
  for (int ks = 0; ks < 4; ++ks)
    qf[ks] = *(const bf16x8*)(&Qp[base + (size_t)qrow * Dd + ks * 16 + hi * 8]);

  f32x16 oacc[2];
#pragma unroll
  for (int i = 0; i < 2; ++i)
#pragma unroll
    for (int r = 0; r < 16; ++r) oacc[i][r] = 0.f;
  float mrun = -1e30f, lrun = 0.f;

  auto stageKV = [&](int t, int buf) {
    const int key0 = t * 64;
#pragma unroll
    for (int j = 0; j < 2; ++j) {
      int rb = (wid * 2 + j) * 8;
      gload_lds16(&Kp[base + (size_t)(key0 + rb + (lane >> 3)) * Dd + src_col(lane)],
                  &Ks[buf][rb * 64]);
      gload_lds16(&VpT[vbase + (size_t)(rb + (lane >> 3)) * Mm + key0 + src_col(lane)],
                  &Vt[buf][rb * 64]);
    }
  };

  stageKV(0, 0);
  float msr = 0.f;
  if (tid < 64) ms[0][tid] = mask[(size_t)b * Ss + tid] * NEG2;
  __syncthreads();

  int cur = 0;
  for (int t = 0; t < NT; ++t) {
    const bool more = (t + 1) < NT;
    if (more) {
      stageKV(t + 1, cur ^ 1);
      if (tid < 64) msr = mask[(size_t)b * Ss + (t + 1) * 64 + tid];
    }
    // S^T = K Q^T : A = K (row=key), B = Q (col=qrow)
    f32x16 sacc[2];
#pragma unroll
    for (int i = 0; i < 2; ++i)
#pragma unroll
      for (int r = 0; r < 16; ++r) sacc[i][r] = 0.f;
    __builtin_amdgcn_s_setprio(1);
#pragma unroll
    for (int sub = 0; sub < 2; ++sub)
#pragma unroll
      for (int ks = 0; ks < 4; ++ks) {
        bf16x8 kf =
            *(const bf16x8*)(&Ks[cur][swz(sub * 32 + l31, ks * 16 + hi * 8)]);
        sacc[sub] = mfma32(kf, qf[ks], sacc[sub]);
      }
    __builtin_amdgcn_s_setprio(0);

    // add mask: key(sub,r) = 32*sub + 8*(r>>2) + 4*hi + (r&3)
    f32x4 mm[2][4];
#pragma unroll
    for (int sub = 0; sub < 2; ++sub)
#pragma unroll
      for (int a = 0; a < 4; ++a)
        mm[sub][a] = *(const f32x4*)(&ms[cur][sub * 32 + a * 8 + hi * 4]);
    float p[2][16];
#pragma unroll
    for (int sub = 0; sub < 2; ++sub)
#pragma unroll
      for (int r = 0; r < 16; ++r)
        p[sub][r] = sacc[sub][r] + mm[sub][r >> 2][r & 3];

    // row max (tree) + cross-half
    float mx[16];
#pragma unroll
    for (int r = 0; r < 16; ++r) mx[r] = fmaxf(p[0][r], p[1][r]);
#pragma unroll
    for (int s = 8; s >= 1; s >>= 1)
#pragma unroll
      for (int r = 0; r < s; ++r) mx[r] = fmaxf(mx[r], mx[r + s]);
    float rm = fmaxf(mx[0], __shfl_xor(mx[0], 32));

    // deferred rescale (T13)
    if (__any(rm > mrun + 10.0f)) {
      const float mnew = fmaxf(mrun, rm);
      const float corr = exp2_fast(mrun - mnew);
      lrun *= corr;
      mrun = mnew;
      redbuf[wid][l31] = corr;  // both halves write same value
      f32x4 cv[4];
#pragma unroll
      for (int a = 0; a < 4; ++a)
        cv[a] = *(const f32x4*)(&redbuf[wid][a * 8 + hi * 4]);
#pragma unroll
      for (int d = 0; d < 2; ++d)
#pragma unroll
        for (int r = 0; r < 16; ++r) oacc[d][r] *= cv[r >> 2][r & 3];
    }
    // exp + row sum
    float sm[16];
#pragma unroll
    for (int sub = 0; sub < 2; ++sub)
#pragma unroll
      for (int r = 0; r < 16; ++r) p[sub][r] = exp2_fast(p[sub][r] - mrun);
#pragma unroll
    for (int r = 0; r < 16; ++r) sm[r] = p[0][r] + p[1][r];
#pragma unroll
    for (int s = 8; s >= 1; s >>= 1)
#pragma unroll
      for (int r = 0; r < s; ++r) sm[r] += sm[r + s];
    lrun += sm[0] + __shfl_xor(sm[0], 32);

    // pack P -> bf16 A-fragments (T12): 16 paired casts + 8 permlane32_swap
    bf16x8 pa[4];
#pragma unroll
    for (int sub = 0; sub < 2; ++sub)
#pragma unroll
      for (int half = 0; half < 2; ++half) {
        const int bse = half * 8;
        unsigned A0 = pack2(p[sub][bse + 0], p[sub][bse + 1]);
        unsigned A1 = pack2(p[sub][bse + 2], p[sub][bse + 3]);
        unsigned B0 = pack2(p[sub][bse + 4], p[sub][bse + 5]);
        unsigned B1 = pack2(p[sub][bse + 6], p[sub][bse + 7]);
        pl32swap(A0, B0);
        pl32swap(A1, B1);
        u32x4 w = {A0, A1, B0, B1};
        pa[sub * 2 + half] = __builtin_bit_cast(bf16x8, w);
      }

    // O += P V : A = pa (row=qrow), B = V^T (col=d, k=key)
    __builtin_amdgcn_s_setprio(1);
#pragma unroll
    for (int dsub = 0; dsub < 2; ++dsub)
#pragma unroll
      for (int ks = 0; ks < 4; ++ks) {
        bf16x8 vf =
            *(const bf16x8*)(&Vt[cur][swz(dsub * 32 + l31, ks * 16 + hi * 8)]);
        oacc[dsub] = mfma32(pa[ks], vf, oacc[dsub]);
      }
    __builtin_amdgcn_s_setprio(0);

    if (more && tid < 64) ms[cur ^ 1][tid] = msr * NEG2;  // T14 late write
    __syncthreads();
    cur ^= 1;
  }

  // epilogue: normalize by 1/lrun[qrow] (broadcast via LDS), store bf16
  redbuf[wid][l31] = 1.0f / lrun;
  f32x4 cv[4];
#pragma unroll
  for (int a = 0; a < 4; ++a)
    cv[a] = *(const f32x4*)(&redbuf[wid][a * 8 + hi * 4]);
#pragma unroll
  for (int dsub = 0; dsub < 2; ++dsub) {
    const int col = h * 64 + dsub * 32 + l31;
#pragma unroll
    for (int r = 0; r < 16; ++r) {
      const int row = q0 + wid * 32 + (r & 3) + 8 * (r >> 2) + 4 * hi;
      Op[((size_t)b * Ss + row) * Dd + col] = bfc(oacc[dsub][r] * cv[r >> 2][r & 3]);
    }
  }
}

}  // namespace

extern "C" void kernel_launch(void* const* d_in, const int* in_sizes, int n_in,
                              void* d_out, int out_size, void* d_ws, size_t ws_size,
                              hipStream_t stream) {
  (void)in_sizes; (void)n_in; (void)out_size; (void)ws_size;
  const float* v = (const float*)d_in[0];
  const float* q = (const float*)d_in[1];
  const float* k = (const float*)d_in[2];
  const float* mask = (const float*)d_in[3];
  const float* Wq = (const float*)d_in[4];
  const float* bq = (const float*)d_in[5];
  const float* Wv = (const float*)d_in[6];
  const float* bv = (const float*)d_in[7];
  const float* Wo = (const float*)d_in[8];
  const float* bo = (const float*)d_in[9];
  float* out = (float*)d_out;

  u16* ws = (u16*)d_ws;
  u16* WqT = ws;
  u16* WvT = WqT + 1024 * 1024;
  u16* WoT = WvT + 1024 * 1024;
  u16* Qp = WoT + 1024 * 1024;
  u16* Kp = Qp + 4096 * 1024;
  u16* VpT = Kp + 4096 * 1024;   // V^T: [1024][4096]
  u16* AO = VpT + 4096 * 1024;   // total 38 MB

  wt_transpose<<<dim3(32, 32, 3), 256, 0, stream>>>(Wq, Wv, Wo, ws);
  // NOTE: reference projects K with the QUERY weights (wQuery(k)).
  proj_qkv<<<dim3(8, 32, 3), 256, 0, stream>>>(q, k, v, WqT, WvT, bq, bv, Qp, Kp, VpT);
  attn32<<<dim3(16, 32), 256, 0, stream>>>(Qp, Kp, VpT, mask, AO);
  gemm_o<<<dim3(16, 32), 256, 0, stream>>>(AO, WoT, bo, out);
}

// Round 5
// 143.777 us; speedup vs baseline: 1.8920x; 1.1190x over previous
//
#include <hip/hip_runtime.h>
#include <cstddef>

// MultiHeadAttentionLayer: B=2, S=2048, D=1024, H=16, DEPTH=64
// R4: (1) panel-grouped XCD swizzle in proj_qkv: all 8 n-tiles of one
//     A-panel run consecutively on ONE XCD (A fetched once into its L2).
//     proj FETCH was 198.7 MB vs ~54 ideal (4x A over-fetch from XCD
//     round-robin). (2) same swizzle in gemm_o. (3) T14: next K-step's A
//     f32 loads issue under the MFMA section in proj. (4) wt_transpose
//     vectorized ushort4 stores. attn32 (now <74us) unchanged.

namespace {

constexpr int Ss = 2048;
constexpr int Dd = 1024;
constexpr int Mm = 4096;  // B*S
constexpr int NT = Ss / 64;
constexpr float QSCALE = 0.18033688f;   // 0.125 / ln2  (base-2 softmax)
constexpr float NEG2 = -1.442695041e9f; // -1e9 / ln2

typedef unsigned short u16;
typedef __attribute__((ext_vector_type(8))) __bf16 bf16x8;
typedef __attribute__((ext_vector_type(4))) float f32x4;
typedef __attribute__((ext_vector_type(16))) float f32x16;
typedef __attribute__((ext_vector_type(4))) unsigned int u32x4;
typedef __attribute__((ext_vector_type(2))) unsigned int u32x2;

__device__ __forceinline__ u16 bfc(float f) {
  __bf16 h = (__bf16)f;  // RNE; pairs into v_cvt_pk_bf16_f32
  return __builtin_bit_cast(u16, h);
}
__device__ __forceinline__ unsigned pack2(float lo, float hi) {
  return (unsigned)bfc(lo) | ((unsigned)bfc(hi) << 16);
}

__device__ __forceinline__ void gload_lds16(const void* g, void* l) {
  __builtin_amdgcn_global_load_lds(
      (__attribute__((address_space(1))) void*)g,
      (__attribute__((address_space(3))) void*)l, 16, 0, 0);
}

__device__ __forceinline__ f32x4 mfma16(bf16x8 a, bf16x8 b, f32x4 c) {
  return __builtin_amdgcn_mfma_f32_16x16x32_bf16(a, b, c, 0, 0, 0);
}
__device__ __forceinline__ f32x16 mfma32(bf16x8 a, bf16x8 b, f32x16 c) {
  return __builtin_amdgcn_mfma_f32_32x32x16_bf16(a, b, c, 0, 0, 0);
}
__device__ __forceinline__ float exp2_fast(float x) {
  return __builtin_amdgcn_exp2f(x);
}

__device__ __forceinline__ void pl32swap(unsigned& a, unsigned& b) {
#if __has_builtin(__builtin_amdgcn_permlane32_swap)
  u32x2 r = __builtin_amdgcn_permlane32_swap(a, b, false, false);
  a = r[0];
  b = r[1];
#else
  unsigned ax = (unsigned)__shfl_xor((int)a, 32);
  unsigned bx = (unsigned)__shfl_xor((int)b, 32);
  bool hi = (threadIdx.x & 63) >= 32;
  unsigned na = hi ? bx : a;
  unsigned nb = hi ? b : ax;
  a = na;
  b = nb;
#endif
}

// swizzled u16 index within a [rows][64 u16] LDS tile (128B rows, 16B chunks)
__device__ __forceinline__ int swz(int row, int col) {
  return row * 64 + ((((col >> 3) ^ (row & 7)) << 3) | (col & 7));
}
// pre-swizzled source column for global_load_lds staging of 8 rows
__device__ __forceinline__ int src_col(int lane) {
  return ((lane & 7) ^ (lane >> 3)) * 8;
}

// ---------------------------------------------------------------- transpose
__global__ __launch_bounds__(256) void wt_transpose(const float* __restrict__ W0,
                                                    const float* __restrict__ W1,
                                                    const float* __restrict__ W2,
                                                    u16* __restrict__ wsbase) {
  const float* W = (blockIdx.z == 0) ? W0 : (blockIdx.z == 1) ? W1 : W2;
  u16* WT = wsbase + (size_t)blockIdx.z * (1024 * 1024);
  __shared__ float tile[32][33];
  const int tid = threadIdx.x;
  const int tx = tid & 31;
  const int ty = tid >> 5;
  const int n0 = blockIdx.x * 32;
  const int k0 = blockIdx.y * 32;
#pragma unroll
  for (int i = 0; i < 4; ++i)
    tile[ty + i * 8][tx] = W[(size_t)(k0 + ty + i * 8) * 1024 + n0 + tx];
  __syncthreads();
  const int r = tid >> 3;
  const int c4 = (tid & 7) * 4;
  ushort4 o4 = make_ushort4(bfc(tile[c4 + 0][r]), bfc(tile[c4 + 1][r]),
                            bfc(tile[c4 + 2][r]), bfc(tile[c4 + 3][r]));
  *(ushort4*)(&WT[(size_t)(n0 + r) * 1024 + k0 + c4]) = o4;
}

// ---------------------------------------------------------------- fused QKV projection
// 1D grid 768, panel-grouped XCD swizzle: xcd = lin&7 owns 12 complete
// m-panels (8 n-tiles each, consecutive). z: 0=Q (scaled), 1=K (Wq! ref
// quirk), 2=V (transposed store). 128x128 tile, BK=64, single-buffered LDS.
__global__ __launch_bounds__(256) void proj_qkv(
    const float* __restrict__ q, const float* __restrict__ k,
    const float* __restrict__ v, const u16* __restrict__ WqT,
    const u16* __restrict__ WvT, const float* __restrict__ bq,
    const float* __restrict__ bv, u16* __restrict__ Qp, u16* __restrict__ Kp,
    u16* __restrict__ VpT) {
  constexpr int K = 1024, N = 1024, M = 4096;
  __shared__ u16 As[128 * 64];
  __shared__ u16 Bs[128 * 64];
  const int lin = (int)blockIdx.x;        // 0..767
  const int xcd = lin & 7;
  const int j = lin >> 3;                 // 0..95
  const int panel = xcd * 12 + (j >> 3);  // 0..95 (bijective)
  const int ntile = j & 7;
  const int z = panel >> 5;               // 0..2
  const int mtile = panel & 31;
  const int n0 = ntile * 128;
  const int m0 = mtile * 128;

  const float* A = (z == 0) ? q : (z == 1) ? k : v;
  const u16* Bt = (z == 2) ? WvT : WqT;
  const float* bias = (z == 2) ? bv : bq;
  const float cscale = (z == 0) ? QSCALE : 1.0f;

  const int tid = threadIdx.x;
  const int wid = tid >> 6;
  const int lane = tid & 63;
  const int g = lane >> 4;
  const int lr = lane & 15;
  const int wr = wid >> 1, wc = wid & 1;

  const f32x4 zero = {0.f, 0.f, 0.f, 0.f};
  f32x4 acc[4][4];
#pragma unroll
  for (int m = 0; m < 4; ++m)
#pragma unroll
    for (int n = 0; n < 4; ++n) acc[m][n] = zero;

  float4 areg[8];
  auto loadA = [&](int kt) {
#pragma unroll
    for (int i = 0; i < 8; ++i) {
      int e = i * 256 + tid;
      int row = e >> 4;
      int c4 = (e & 15) << 2;
      areg[i] = *(const float4*)(&A[(size_t)(m0 + row) * K + kt * 64 + c4]);
    }
  };
  auto writeA = [&]() {
#pragma unroll
    for (int i = 0; i < 8; ++i) {
      int e = i * 256 + tid;
      int row = e >> 4;
      int c4 = (e & 15) << 2;
      ushort4 o4 = make_ushort4(bfc(areg[i].x), bfc(areg[i].y), bfc(areg[i].z),
                                bfc(areg[i].w));
      *(ushort4*)(&As[swz(row, c4)]) = o4;
    }
  };

  loadA(0);
  for (int kt = 0; kt < 16; ++kt) {
    writeA();
#pragma unroll
    for (int jj = 0; jj < 4; ++jj) {
      int rb = (wid * 4 + jj) * 8;
      gload_lds16(&Bt[(size_t)(n0 + rb + (lane >> 3)) * K + kt * 64 + src_col(lane)],
                  &Bs[rb * 64]);
    }
    __syncthreads();
    if (kt + 1 < 16) loadA(kt + 1);  // T14: latency hides under MFMA below
#pragma unroll
    for (int kk = 0; kk < 2; ++kk) {
      bf16x8 a[4], b[4];
#pragma unroll
      for (int m = 0; m < 4; ++m)
        a[m] = *(const bf16x8*)(&As[swz(wr * 64 + m * 16 + lr, kk * 32 + g * 8)]);
#pragma unroll
      for (int n = 0; n < 4; ++n)
        b[n] = *(const bf16x8*)(&Bs[swz(wc * 64 + n * 16 + lr, kk * 32 + g * 8)]);
#pragma unroll
      for (int m = 0; m < 4; ++m)
#pragma unroll
        for (int n = 0; n < 4; ++n) acc[m][n] = mfma16(a[m], b[n], acc[m][n]);
    }
    __syncthreads();
  }

#pragma unroll
  for (int n = 0; n < 4; ++n) {
    const int col = n0 + wc * 64 + n * 16 + lr;
    const float bv_ = bias[col];
#pragma unroll
    for (int m = 0; m < 4; ++m) {
      const int rowb = m0 + wr * 64 + m * 16 + g * 4;
      if (z == 2) {
        ushort4 o4 = make_ushort4(bfc(acc[m][n][0] + bv_), bfc(acc[m][n][1] + bv_),
                                  bfc(acc[m][n][2] + bv_), bfc(acc[m][n][3] + bv_));
        *(ushort4*)(&VpT[(size_t)col * M + rowb]) = o4;
      } else {
        u16* Cp = (z == 0) ? Qp : Kp;
#pragma unroll
        for (int r = 0; r < 4; ++r)
          Cp[(size_t)(rowb + r) * N + col] = bfc((acc[m][n][r] + bv_) * cscale);
      }
    }
  }
}

// ---------------------------------------------------------------- O-GEMM
// out = AO @ WoT^T + bo (f32). 128x64 tile; 1D grid 512, panel-grouped
// XCD swizzle (each XCD owns 4 complete AO m-panels).
__global__ __launch_bounds__(256) void gemm_o(const u16* __restrict__ Ap,
                                              const u16* __restrict__ Bt,
                                              const float* __restrict__ bias,
                                              float* __restrict__ Cp) {
  constexpr int K = 1024, N = 1024;
  __shared__ u16 As[128 * 64];
  __shared__ u16 Bs[64 * 64];
  const int lin = (int)blockIdx.x;       // 0..511
  const int xcd = lin & 7;
  const int j = lin >> 3;                // 0..63
  const int mtile = xcd * 4 + (j >> 4);  // 0..31
  const int ntile = j & 15;
  const int n0 = ntile * 64;
  const int m0 = mtile * 128;

  const int tid = threadIdx.x;
  const int wid = tid >> 6;
  const int lane = tid & 63;
  const int g = lane >> 4;
  const int lr = lane & 15;

  const f32x4 zero = {0.f, 0.f, 0.f, 0.f};
  f32x4 acc[2][4];
#pragma unroll
  for (int m = 0; m < 2; ++m)
#pragma unroll
    for (int n = 0; n < 4; ++n) acc[m][n] = zero;

  for (int k0 = 0; k0 < K; k0 += 64) {
#pragma unroll
    for (int jj = 0; jj < 4; ++jj) {
      int rb = (wid * 4 + jj) * 8;
      gload_lds16(&Ap[(size_t)(m0 + rb + (lane >> 3)) * K + k0 + src_col(lane)],
                  &As[rb * 64]);
    }
#pragma unroll
    for (int jj = 0; jj < 2; ++jj) {
      int rb = (wid * 2 + jj) * 8;
      gload_lds16(&Bt[(size_t)(n0 + rb + (lane >> 3)) * K + k0 + src_col(lane)],
                  &Bs[rb * 64]);
    }
    __syncthreads();
#pragma unroll
    for (int kk = 0; kk < 2; ++kk) {
      bf16x8 a[2], b[4];
#pragma unroll
      for (int m = 0; m < 2; ++m)
        a[m] = *(const bf16x8*)(&As[swz(wid * 32 + m * 16 + lr, kk * 32 + g * 8)]);
#pragma unroll
      for (int n = 0; n < 4; ++n)
        b[n] = *(const bf16x8*)(&Bs[swz(n * 16 + lr, kk * 32 + g * 8)]);
#pragma unroll
      for (int m = 0; m < 2; ++m)
#pragma unroll
        for (int n = 0; n < 4; ++n) acc[m][n] = mfma16(a[m], b[n], acc[m][n]);
    }
    __syncthreads();
  }
#pragma unroll
  for (int n = 0; n < 4; ++n) {
    const int col = n0 + n * 16 + lr;
    const float bv_ = bias[col];
#pragma unroll
    for (int m = 0; m < 2; ++m) {
      const int rowb = m0 + wid * 32 + m * 16 + g * 4;
#pragma unroll
      for (int r = 0; r < 4; ++r)
        Cp[(size_t)(rowb + r) * N + col] = acc[m][n][r] + bv_;
    }
  }
}

// ---------------------------------------------------------------- attention
// 32x32x16 swapped-QK^T flash attention (unchanged from R3).
__global__ __launch_bounds__(256) void attn32(const u16* __restrict__ Qp,
                                              const u16* __restrict__ Kp,
                                              const u16* __restrict__ VpT,
                                              const float* __restrict__ mask,
                                              u16* __restrict__ Op) {
  __shared__ u16 Ks[2][64 * 64];  // [key][d]  (swizzled)
  __shared__ u16 Vt[2][64 * 64];  // [d][key]  (swizzled)
  __shared__ float ms[2][64];     // mask * (-1e9/ln2)
  __shared__ float redbuf[4][32]; // per-wave row-broadcast buffer
  const int tid = threadIdx.x;
  const int wid = tid >> 6;
  const int lane = tid & 63;
  const int l31 = lane & 31;
  const int hi = lane >> 5;
  const int lin = (int)(blockIdx.x + (blockIdx.y << 4));  // grid (16,32)
  const int wl = (lin & 7) * 64 + (lin >> 3);
  const int qt = wl & 15;
  const int bh = wl >> 4;
  const int b = bh >> 4;
  const int h = bh & 15;
  const int q0 = qt * 128;
  const size_t base = ((size_t)b * Ss) * Dd + (size_t)h * 64;
  const size_t vbase = (size_t)h * 64 * Mm + (size_t)b * Ss;
  const int qrow = q0 + wid * 32 + l31;

  bf16x8 qf[4];
#pragma unroll
  for (int ks = 0; ks < 4; ++ks)
    qf[ks] = *(const bf16x8*)(&Qp[base + (size_t)qrow * Dd + ks * 16 + hi * 8]);

  f32x16 oacc[2];
#pragma unroll
  for (int i = 0; i < 2; ++i)
#pragma unroll
    for (int r = 0; r < 16; ++r) oacc[i][r] = 0.f;
  float mrun = -1e30f, lrun = 0.f;

  auto stageKV = [&](int t, int buf) {
    const int key0 = t * 64;
#pragma unroll
    for (int jj = 0; jj < 2; ++jj) {
      int rb = (wid * 2 + jj) * 8;
      gload_lds16(&Kp[base + (size_t)(key0 + rb + (lane >> 3)) * Dd + src_col(lane)],
                  &Ks[buf][rb * 64]);
      gload_lds16(&VpT[vbase + (size_t)(rb + (lane >> 3)) * Mm + key0 + src_col(lane)],
                  &Vt[buf][rb * 64]);
    }
  };

  stageKV(0, 0);
  float msr = 0.f;
  if (tid < 64) ms[0][tid] = mask[(size_t)b * Ss + tid] * NEG2;
  __syncthreads();

  int cur = 0;
  for (int t = 0; t < NT; ++t) {
    const bool more = (t + 1) < NT;
    if (more) {
      stageKV(t + 1, cur ^ 1);
      if (tid < 64) msr = mask[(size_t)b * Ss + (t + 1) * 64 + tid];
    }
    f32x16 sacc[2];
#pragma unroll
    for (int i = 0; i < 2; ++i)
#pragma unroll
      for (int r = 0; r < 16; ++r) sacc[i][r] = 0.f;
    __builtin_amdgcn_s_setprio(1);
#pragma unroll
    for (int sub = 0; sub < 2; ++sub)
#pragma unroll
      for (int ks = 0; ks < 4; ++ks) {
        bf16x8 kf =
            *(const bf16x8*)(&Ks[cur][swz(sub * 32 + l31, ks * 16 + hi * 8)]);
        sacc[sub] = mfma32(kf, qf[ks], sacc[sub]);
      }
    __builtin_amdgcn_s_setprio(0);

    f32x4 mm[2][4];
#pragma unroll
    for (int sub = 0; sub < 2; ++sub)
#pragma unroll
      for (int a = 0; a < 4; ++a)
        mm[sub][a] = *(const f32x4*)(&ms[cur][sub * 32 + a * 8 + hi * 4]);
    float p[2][16];
#pragma unroll
    for (int sub = 0; sub < 2; ++sub)
#pragma unroll
      for (int r = 0; r < 16; ++r)
        p[sub][r] = sacc[sub][r] + mm[sub][r >> 2][r & 3];

    float mx[16];
#pragma unroll
    for (int r = 0; r < 16; ++r) mx[r] = fmaxf(p[0][r], p[1][r]);
#pragma unroll
    for (int s = 8; s >= 1; s >>= 1)
#pragma unroll
      for (int r = 0; r < s; ++r) mx[r] = fmaxf(mx[r], mx[r + s]);
    float rm = fmaxf(mx[0], __shfl_xor(mx[0], 32));

    if (__any(rm > mrun + 10.0f)) {
      const float mnew = fmaxf(mrun, rm);
      const float corr = exp2_fast(mrun - mnew);
      lrun *= corr;
      mrun = mnew;
      redbuf[wid][l31] = corr;
      f32x4 cv[4];
#pragma unroll
      for (int a = 0; a < 4; ++a)
        cv[a] = *(const f32x4*)(&redbuf[wid][a * 8 + hi * 4]);
#pragma unroll
      for (int d = 0; d < 2; ++d)
#pragma unroll
        for (int r = 0; r < 16; ++r) oacc[d][r] *= cv[r >> 2][r & 3];
    }
    float sm[16];
#pragma unroll
    for (int sub = 0; sub < 2; ++sub)
#pragma unroll
      for (int r = 0; r < 16; ++r) p[sub][r] = exp2_fast(p[sub][r] - mrun);
#pragma unroll
    for (int r = 0; r < 16; ++r) sm[r] = p[0][r] + p[1][r];
#pragma unroll
    for (int s = 8; s >= 1; s >>= 1)
#pragma unroll
      for (int r = 0; r < s; ++r) sm[r] += sm[r + s];
    lrun += sm[0] + __shfl_xor(sm[0], 32);

    bf16x8 pa[4];
#pragma unroll
    for (int sub = 0; sub < 2; ++sub)
#pragma unroll
      for (int half = 0; half < 2; ++half) {
        const int bse = half * 8;
        unsigned A0 = pack2(p[sub][bse + 0], p[sub][bse + 1]);
        unsigned A1 = pack2(p[sub][bse + 2], p[sub][bse + 3]);
        unsigned B0 = pack2(p[sub][bse + 4], p[sub][bse + 5]);
        unsigned B1 = pack2(p[sub][bse + 6], p[sub][bse + 7]);
        pl32swap(A0, B0);
        pl32swap(A1, B1);
        u32x4 w = {A0, A1, B0, B1};
        pa[sub * 2 + half] = __builtin_bit_cast(bf16x8, w);
      }

    __builtin_amdgcn_s_setprio(1);
#pragma unroll
    for (int dsub = 0; dsub < 2; ++dsub)
#pragma unroll
      for (int ks = 0; ks < 4; ++ks) {
        bf16x8 vf =
            *(const bf16x8*)(&Vt[cur][swz(dsub * 32 + l31, ks * 16 + hi * 8)]);
        oacc[dsub] = mfma32(pa[ks], vf, oacc[dsub]);
      }
    __builtin_amdgcn_s_setprio(0);

    if (more && tid < 64) ms[cur ^ 1][tid] = msr * NEG2;
    __syncthreads();
    cur ^= 1;
  }

  redbuf[wid][l31] = 1.0f / lrun;
  f32x4 cv[4];
#pragma unroll
  for (int a = 0; a < 4; ++a)
    cv[a] = *(const f32x4*)(&redbuf[wid][a * 8 + hi * 4]);
#pragma unroll
  for (int dsub = 0; dsub < 2; ++dsub) {
    const int col = h * 64 + dsub * 32 + l31;
#pragma unroll
    for (int r = 0; r < 16; ++r) {
      const int row = q0 + wid * 32 + (r & 3) + 8 * (r >> 2) + 4 * hi;
      Op[((size_t)b * Ss + row) * Dd + col] = bfc(oacc[dsub][r] * cv[r >> 2][r & 3]);
    }
  }
}

}  // namespace

extern "C" void kernel_launch(void* const* d_in, const int* in_sizes, int n_in,
                              void* d_out, int out_size, void* d_ws, size_t ws_size,
                              hipStream_t stream) {
  (void)in_sizes; (void)n_in; (void)out_size; (void)ws_size;
  const float* v = (const float*)d_in[0];
  const float* q = (const float*)d_in[1];
  const float* k = (const float*)d_in[2];
  const float* mask = (const float*)d_in[3];
  const float* Wq = (const float*)d_in[4];
  const float* bq = (const float*)d_in[5];
  const float* Wv = (const float*)d_in[6];
  const float* bv = (const float*)d_in[7];
  const float* Wo = (const float*)d_in[8];
  const float* bo = (const float*)d_in[9];
  float* out = (float*)d_out;

  u16* ws = (u16*)d_ws;
  u16* WqT = ws;
  u16* WvT = WqT + 1024 * 1024;
  u16* WoT = WvT + 1024 * 1024;
  u16* Qp = WoT + 1024 * 1024;
  u16* Kp = Qp + 4096 * 1024;
  u16* VpT = Kp + 4096 * 1024;   // V^T: [1024][4096]
  u16* AO = VpT + 4096 * 1024;   // total 38 MB

  wt_transpose<<<dim3(32, 32, 3), 256, 0, stream>>>(Wq, Wv, Wo, ws);
  // NOTE: reference projects K with the QUERY weights (wQuery(k)).
  proj_qkv<<<dim3(768), 256, 0, stream>>>(q, k, v, WqT, WvT, bq, bv, Qp, Kp, VpT);
  attn32<<<dim3(16, 32), 256, 0, stream>>>(Qp, Kp, VpT, mask, AO);
  gemm_o<<<dim3(512), 256, 0, stream>>>(AO, WoT, bo, out);
}